// Round 18
// baseline (370.763 us; speedup 1.0000x reference)
//
#include <hip/hip_runtime.h>
#include <hip/hip_bf16.h>

#define EPSF 1e-20f

using short8  = __attribute__((ext_vector_type(8))) short;
using float4f = __attribute__((ext_vector_type(4))) float;
typedef const __attribute__((address_space(1))) unsigned int* gas_t;
typedef __attribute__((address_space(3))) unsigned int* las_t;

__device__ __forceinline__ unsigned short f2bf(float f) {
    __hip_bfloat16 h = __float2bfloat16(f);
    return __builtin_bit_cast(unsigned short, h);
}
__device__ __forceinline__ float bf2f(unsigned short u) {
    __hip_bfloat16 h = __builtin_bit_cast(__hip_bfloat16, u);
    return __bfloat162float(h);
}
__device__ __forceinline__ float frcp(float x) { return __builtin_amdgcn_rcpf(x); }

// ---------------------------------------------------------------------------
// Unified weight prep (one launch, 472 blocks):
//  blocks [0,424): linear idx
//    [992,107488)    : MFMA A-fragments for w2..w6 (bf16, lane-exact order)
//    [107488,108512) : conv1 A-fragments wf1 (taps-as-K, K padded 25->32
//                      with ZEROS)
//  blocks [424,472): one WAVE per (layer,co) reciprocal weight sum
//  block 0 also zeroes the 16-B zero page (OOB target for global_load_lds).
// ---------------------------------------------------------------------------
__global__ void wprep_k(const float* __restrict__ w1, const float* __restrict__ w2,
                        const float* __restrict__ w3, const float* __restrict__ w4,
                        const float* __restrict__ w5, const float* __restrict__ w6,
                        float* __restrict__ is1, float* __restrict__ is2,
                        float* __restrict__ is3, float* __restrict__ is4,
                        float* __restrict__ is5, float* __restrict__ is6,
                        unsigned short* __restrict__ wf2, unsigned short* __restrict__ wf3,
                        unsigned short* __restrict__ wf4, unsigned short* __restrict__ wf5,
                        unsigned short* __restrict__ wf6, unsigned short* __restrict__ wf1,
                        unsigned int* __restrict__ zpage) {
    const int tid = threadIdx.x;
    if (blockIdx.x == 0 && tid < 4) zpage[tid] = 0;   // 16-B zero page
    if (blockIdx.x >= 424) {
        int wid = (blockIdx.x - 424) * 4 + (tid >> 6);
        if (wid >= 192) return;
        int task = wid >> 5, co = wid & 31, lane = tid & 63;
        const float* w; int n; float* s;
        switch (task) {
            case 0: w = w1; n = 25;  s = is1; break;
            case 1: w = w2; n = 800; s = is2; break;
            case 2: w = w3; n = 800; s = is3; break;
            case 3: w = w4; n = 576; s = is4; break;
            case 4: w = w5; n = 576; s = is5; break;
            default: w = w6; n = 576; s = is6; break;
        }
        float acc = 0.f;
        for (int i = lane; i < n; i += 64) acc += w[co * n + i];
#pragma unroll
        for (int off = 1; off < 64; off <<= 1) acc += __shfl_xor(acc, off);
        if (lane == 0) s[co] = 1.0f / acc;
        return;
    }
    int idx = blockIdx.x * 256 + tid;
    if (idx < 992) return;
    int r = idx - 992;
    if (r >= 106496) {                      // conv1 fragments (taps-as-K)
        int r2 = r - 106496;
        if (r2 >= 1024) return;
        int j = r2 & 7, lane = (r2 >> 3) & 63, cot = (r2 >> 9) & 1;
        int co = cot * 16 + (lane & 15);
        int tap = (lane >> 4) * 8 + j;
        wf1[r2] = f2bf(tap < 25 ? w1[co * 25 + tap] : 0.f);
        return;
    }
    const float* w; unsigned short* wf; int CIN, KK, cxor;
    if (r < 25600)        {             w = w2; wf = wf2; CIN = 32; KK = 25; cxor = 0;  }
    else if (r < 51200)   { r -= 25600; w = w3; wf = wf3; CIN = 32; KK = 25; cxor = 0;  }
    else if (r < 69632)   { r -= 51200; w = w4; wf = wf4; CIN = 64; KK = 9;  cxor = 0;  }
    else if (r < 88064)   { r -= 69632; w = w5; wf = wf5; CIN = 64; KK = 9;  cxor = 0;  }
    else                  { r -= 88064; w = w6; wf = wf6; CIN = 64; KK = 9;  cxor = 32; }
    int j = r & 7, lane = (r >> 3) & 63, cot = (r >> 9) & 1, ks = r >> 10;
    int phase = ks / KK, tap = ks - phase * KK;
    int co = cot * 16 + (lane & 15);
    int ci = (phase * 32 + (lane >> 4) * 8 + j) ^ cxor;
    wf[r] = f2bf(w[((long)co * CIN + ci) * KK + tap]);
}

// ---------------------------------------------------------------------------
// conv1: CIN=1 nconv as ONE MFMA k-step with taps-as-K (R17, unchanged).
// ---------------------------------------------------------------------------
__global__ __launch_bounds__(256)
void conv1_k(const float* __restrict__ x, const unsigned short* __restrict__ wf1,
             const float* __restrict__ bias, const float* __restrict__ is_,
             unsigned short* __restrict__ out, int H, int W) {
    constexpr int TIW = 20, TIH = 14, TSZ = TIW * TIH;   // 280
    __shared__ unsigned short sp[TSZ], sc_[TSZ];
    __shared__ unsigned short lbb[128 * 32];             // 8 KB bounce
    const int tid = threadIdx.x;
    const int wv = tid >> 6, lane = tid & 63, n = lane & 15, q = lane >> 4;
    const int ox0 = blockIdx.x * 16, oy0 = blockIdx.y * 8, b = blockIdx.z;
    const long HW = (long)H * W;
    const float* xd = x + (long)(b * 2) * HW;
    const float* xc = xd + HW;

    for (int i = tid; i < TSZ; i += 256) {
        int py = i / TIW, px = i - py * TIW;
        int gy = oy0 - 2 + py, gx = ox0 - 2 + px;
        float c = 0.f, d = 0.f;
        if (gy >= 0 && gy < H && gx >= 0 && gx < W) {
            long g = (long)gy * W + gx;
            c = xc[g]; d = xd[g];
        }
        sc_[i] = f2bf(c);
        sp[i] = f2bf(d * c);
    }
    __syncthreads();

    int loff[8];                      // per-lane tap offsets (k = q*8+j)
#pragma unroll
    for (int j = 0; j < 8; ++j) {
        int k = q * 8 + j;
        int dy = k / 5, dx = k - 5 * dy;
        loff[j] = dy * TIW + dx;
    }
    short8 a0 = ((const short8*)wf1)[0 * 64 + lane];
    short8 a1 = ((const short8*)wf1)[1 * 64 + lane];

    float4f accP[2][2], accC[2][2];
#pragma unroll
    for (int mt = 0; mt < 2; ++mt) {
        const int rb = (2 * wv + mt) * TIW + n;
        union { short8 v; unsigned short s[8]; } bp, bc;
#pragma unroll
        for (int j = 0; j < 8; ++j) {
            bp.s[j] = sp[rb + loff[j]];
            bc.s[j] = sc_[rb + loff[j]];
        }
        accP[mt][0] = __builtin_amdgcn_mfma_f32_16x16x32_bf16(a0, bp.v, (float4f)0.f, 0, 0, 0);
        accP[mt][1] = __builtin_amdgcn_mfma_f32_16x16x32_bf16(a1, bp.v, (float4f)0.f, 0, 0, 0);
        accC[mt][0] = __builtin_amdgcn_mfma_f32_16x16x32_bf16(a0, bc.v, (float4f)0.f, 0, 0, 0);
        accC[mt][1] = __builtin_amdgcn_mfma_f32_16x16x32_bf16(a1, bc.v, (float4f)0.f, 0, 0, 0);
    }

    float4f b4[2], s4[2];
    b4[0] = *(const float4f*)(bias + q * 4);
    b4[1] = *(const float4f*)(bias + 16 + q * 4);
    s4[0] = *(const float4f*)(is_ + q * 4);
    s4[1] = *(const float4f*)(is_ + 16 + q * 4);

#pragma unroll
    for (int pl = 0; pl < 2; ++pl) {
        __syncthreads();
#pragma unroll
        for (int mt = 0; mt < 2; ++mt) {
            const int pix = (2 * wv + mt) * 16 + n;
#pragma unroll
            for (int ct = 0; ct < 2; ++ct) {
                unsigned int w0, w1v;
                if (pl == 0) {
                    float d0 = accC[mt][ct][0], d1 = accC[mt][ct][1];
                    float d2 = accC[mt][ct][2], d3 = accC[mt][ct][3];
                    float x0 = fmaf(accP[mt][ct][0], frcp(d0 + EPSF), b4[ct][0]) * (d0 * s4[ct][0]);
                    float x1 = fmaf(accP[mt][ct][1], frcp(d1 + EPSF), b4[ct][1]) * (d1 * s4[ct][1]);
                    float x2 = fmaf(accP[mt][ct][2], frcp(d2 + EPSF), b4[ct][2]) * (d2 * s4[ct][2]);
                    float x3 = fmaf(accP[mt][ct][3], frcp(d3 + EPSF), b4[ct][3]) * (d3 * s4[ct][3]);
                    w0 = (unsigned int)f2bf(x0) | ((unsigned int)f2bf(x1) << 16);
                    w1v = (unsigned int)f2bf(x2) | ((unsigned int)f2bf(x3) << 16);
                } else {
                    float c0 = accC[mt][ct][0] * s4[ct][0], c1 = accC[mt][ct][1] * s4[ct][1];
                    float c2 = accC[mt][ct][2] * s4[ct][2], c3 = accC[mt][ct][3] * s4[ct][3];
                    w0 = (unsigned int)f2bf(c0) | ((unsigned int)f2bf(c1) << 16);
                    w1v = (unsigned int)f2bf(c2) | ((unsigned int)f2bf(c3) << 16);
                }
                uint2 v; v.x = w0; v.y = w1v;
                *(uint2*)(lbb + pix * 32 +
                          ((ct * 2 + (q >> 1) + n + (n >> 2)) & 3) * 8 + (q & 1) * 4) = v;
            }
        }
        __syncthreads();
        const unsigned short* obase = out + (long)(b * 2 + pl) * HW * 32;
#pragma unroll
        for (int it = 0; it < 2; ++it) {
            int off = it * 256 + tid;          // 16B units
            int pix = off >> 2, sub = off & 3;
            uint4 v = *(const uint4*)(lbb + pix * 32 + ((sub + pix + (pix >> 2)) & 3) * 8);
            int ry = pix >> 4, rx = pix & 15;
            *(uint4*)(obase + ((long)(oy0 + ry) * W + ox0 + rx) * 32 + sub * 8) = v;
        }
    }
}

// ---------------------------------------------------------------------------
// MFMA implicit-GEMM nconv (channel-last bf16 [b*2+pc][y][x][32ci]).
// 16x8 output tile, 256 thr = 4 waves; wave wv owns rows {2wv,2wv+1}
// (mt = row), 16 px each. Tap loop: ROW-REUSE (dx-outer / row-inner).
// Staging via global_load_lds width=16 DMA (linear LDS, zero page OOB).
// R18 — SPLIT-PLANE PIPELINE: accP only reads the p-plane, accC only the
// c-plane, so each plane's DMA is issued and then OVERLAPPED with the other
// plane's tap loop (the m97 barrier-drain stall, hidden via the problem's
// P/C independence). Chain for NPH=2: p0 | bar | +c0, tapsP0 | bar | +p1,
// tapsC0 | bar | +c1, tapsP1 | bar | tapsC1 — every DMA except the first
// overlaps compute. A-frags re-read once per plane pass (L1-hit).
// POOL: fused 2x2 stride-2 max-pool. FUSE7 fuses the final 1x1 nconv.
// Epilogue bounces through LDS for full-line uint4 global writes.
// ---------------------------------------------------------------------------
template <int KS, int NPH, bool FUSE7, bool POOL>
__global__ __launch_bounds__(256, 4)
void mconv_k(const unsigned short* __restrict__ s1,
             const unsigned short* __restrict__ s2,
             const unsigned short* __restrict__ wf,
             const float* __restrict__ bias, const float* __restrict__ sden,
             unsigned short* __restrict__ out, float* __restrict__ xout,
             const float* __restrict__ w7, const float* __restrict__ b7,
             unsigned short* __restrict__ pout,
             const unsigned int* __restrict__ zpage,
             int H, int W) {
    constexpr int R = KS / 2, KK = KS * KS;
    constexpr int TIH = 8 + KS - 1, TIW = 16 + KS - 1;    // 12x20 (KS=5) / 10x18 (KS=3)
    constexpr int PCS = TIH * TIW * 32;        // ushorts per plane region
    constexpr int NCH = TIH * TIW * 4;         // 16B chunks per plane
    __shared__ unsigned short lds[2 * PCS];

    const int tid = threadIdx.x;
    const int wv = tid >> 6, lane = tid & 63, n = lane & 15, q = lane >> 4;
    const int ox0 = blockIdx.x * 16, oy0 = blockIdx.y * 8, b = blockIdx.z;
    const long HW = (long)H * W;

    float4f accP[2][2], accC[2][2];
#pragma unroll
    for (int mt = 0; mt < 2; ++mt)
#pragma unroll
        for (int ct = 0; ct < 2; ++ct) {
            accP[mt][ct] = (float4f)0.f;
            accC[mt][ct] = (float4f)0.f;
        }

    const int PB = (2 * wv) * TIW + n;   // lane pixel base (2 rows per wave)

    // issue one plane's staging DMA into region pl (no wait)
    auto stage = [&](int pl, int ph) {
        const unsigned short* src = (NPH == 2 && ph == 1) ? s2 : s1;
        for (int it = 0; it < (NCH + 255) / 256; ++it) {
            int ch = it * 256 + tid;
            if (ch < NCH) {
                int pix = ch >> 2, k8 = ch & 3;
                int py = pix / TIW, px = pix - py * TIW;
                int gy = oy0 - R + py, gx = ox0 - R + px;
                const unsigned short* ga;
                if (gy >= 0 && gy < H && gx >= 0 && gx < W) {
                    long gi;
                    if (NPH == 2 && ph == 1)
                        gi = ((long)(b * 2 + pl) * (HW >> 2) +
                              (long)(gy >> 1) * (W >> 1) + (gx >> 1)) * 32 + k8 * 8;
                    else
                        gi = ((long)(b * 2 + pl) * HW + (long)gy * W + gx) * 32 + k8 * 8;
                    ga = src + gi;
                } else {
                    ga = (const unsigned short*)zpage;
                }
                __builtin_amdgcn_global_load_lds(
                    (gas_t)ga,
                    (las_t)(lds + (size_t)pl * PCS + (size_t)(it * 256 + wv * 64) * 8),
                    16, 0, 0);
            }
        }
    };

    // tap loop over one plane region (dx-outer / row-inner, row-reuse)
    auto taps = [&](float4f (&acc)[2][2], int region, int ph) {
        const int base = region * PCS;
#pragma unroll
        for (int dx = 0; dx < KS; ++dx) {
            short8 a0p, a1p;   // A-frags of previous row's tap (mt=1 operand)
#pragma unroll
            for (int r = 0; r < KS + 1; ++r) {
                short8 a0c, a1c;
                if (r < KS) {
                    const int ks = ph * KK + r * KS + dx;
                    a0c = ((const short8*)wf)[(ks * 2 + 0) * 64 + lane];
                    a1c = ((const short8*)wf)[(ks * 2 + 1) * 64 + lane];
                }
                short8 bb = *(const short8*)(lds + base + (PB + r * TIW + dx) * 32 + q * 8);
                if (r < KS) {   // mt=0, dy=r
                    acc[0][0] = __builtin_amdgcn_mfma_f32_16x16x32_bf16(a0c, bb, acc[0][0], 0, 0, 0);
                    acc[0][1] = __builtin_amdgcn_mfma_f32_16x16x32_bf16(a1c, bb, acc[0][1], 0, 0, 0);
                }
                if (r >= 1) {   // mt=1, dy=r-1
                    acc[1][0] = __builtin_amdgcn_mfma_f32_16x16x32_bf16(a0p, bb, acc[1][0], 0, 0, 0);
                    acc[1][1] = __builtin_amdgcn_mfma_f32_16x16x32_bf16(a1p, bb, acc[1][1], 0, 0, 0);
                }
                a0p = a0c; a1p = a1c;
            }
        }
    };

    // ---- pipelined main: each DMA (after the first) overlaps a tap loop ----
    stage(0, 0);            // p0 -> region0
    __syncthreads();        // p0 ready
    stage(1, 0);            // issue c0 -> region1 (completes during tapsP0)
    taps(accP, 0, 0);
    __syncthreads();        // c0 ready; all waves done reading region0
    if (NPH == 2) {
        stage(0, 1);        // issue p1 -> region0 (overlaps tapsC0)
        taps(accC, 1, 0);
        __syncthreads();    // p1 ready; all done reading region1
        stage(1, 1);        // issue c1 -> region1 (overlaps tapsP1)
        taps(accP, 0, 1);
        __syncthreads();    // c1 ready
        taps(accC, 1, 1);
    } else {
        taps(accC, 1, 0);
    }

    // ---- epilogue ----
    float4f b4[2], s4[2];
    b4[0] = *(const float4f*)(bias + q * 4);
    b4[1] = *(const float4f*)(bias + 16 + q * 4);
    s4[0] = *(const float4f*)(sden + q * 4);
    s4[1] = *(const float4f*)(sden + 16 + q * 4);

    if (!FUSE7) {
        // ---- fused 2x2 pool (before the bounce; accs still live) ----
        if (POOL) {
            const int W2 = W >> 1;
            const long HW4 = HW >> 2;
#pragma unroll
            for (int ct = 0; ct < 2; ++ct) {
                unsigned int pw[2], cw[2];
                unsigned short ps[4], cs[4];
#pragma unroll
                for (int r = 0; r < 4; ++r) {
                    float d0 = accC[0][ct][r], d1 = accC[1][ct][r];
                    float c00 = d0 * s4[ct][r];
                    float c10 = d1 * s4[ct][r];
                    float p00 = fmaf(accP[0][ct][r], frcp(d0 + EPSF), b4[ct][r]) * c00;
                    float p10 = fmaf(accP[1][ct][r], frcp(d1 + EPSF), b4[ct][r]) * c10;
                    float c01 = __shfl_xor(c00, 1), c11 = __shfl_xor(c10, 1);
                    float p01 = __shfl_xor(p00, 1), p11 = __shfl_xor(p10, 1);
                    float bc = c00, bp = p00;                 // first-max, row-major
                    if (c01 > bc) { bc = c01; bp = p01; }
                    if (c10 > bc) { bc = c10; bp = p10; }
                    if (c11 > bc) { bc = c11; bp = p11; }
                    ps[r] = f2bf(bp * 0.25f);
                    cs[r] = f2bf(bc * 0.25f);
                }
                if (!(n & 1)) {
                    pw[0] = (unsigned int)ps[0] | ((unsigned int)ps[1] << 16);
                    pw[1] = (unsigned int)ps[2] | ((unsigned int)ps[3] << 16);
                    cw[0] = (unsigned int)cs[0] | ((unsigned int)cs[1] << 16);
                    cw[1] = (unsigned int)cs[2] | ((unsigned int)cs[3] << 16);
                    int gy2 = (oy0 >> 1) + wv, gx2 = (ox0 >> 1) + (n >> 1);
                    long pb = ((long)gy2 * W2 + gx2) * 32 + ct * 16 + q * 4;
                    uint2 vp; vp.x = pw[0]; vp.y = pw[1];
                    uint2 vc; vc.x = cw[0]; vc.y = cw[1];
                    *(uint2*)(pout + (long)(b * 2 + 0) * HW4 * 32 + pb) = vp;
                    *(uint2*)(pout + (long)(b * 2 + 1) * HW4 * 32 + pb) = vc;
                }
            }
        }
        // ---- LDS bounce, one plane at a time (own swizzled layout) ----
#pragma unroll
        for (int pl = 0; pl < 2; ++pl) {
            __syncthreads();
#pragma unroll
            for (int mt = 0; mt < 2; ++mt) {
                const int pix = (2 * wv + mt) * 16 + n;
#pragma unroll
                for (int ct = 0; ct < 2; ++ct) {
                    unsigned int w0, w1;
                    if (pl == 0) {
                        float d0 = accC[mt][ct][0], d1 = accC[mt][ct][1];
                        float d2 = accC[mt][ct][2], d3 = accC[mt][ct][3];
                        float x0 = fmaf(accP[mt][ct][0], frcp(d0 + EPSF), b4[ct][0]) * (d0 * s4[ct][0]);
                        float x1 = fmaf(accP[mt][ct][1], frcp(d1 + EPSF), b4[ct][1]) * (d1 * s4[ct][1]);
                        float x2 = fmaf(accP[mt][ct][2], frcp(d2 + EPSF), b4[ct][2]) * (d2 * s4[ct][2]);
                        float x3 = fmaf(accP[mt][ct][3], frcp(d3 + EPSF), b4[ct][3]) * (d3 * s4[ct][3]);
                        w0 = (unsigned int)f2bf(x0) | ((unsigned int)f2bf(x1) << 16);
                        w1 = (unsigned int)f2bf(x2) | ((unsigned int)f2bf(x3) << 16);
                    } else {
                        float c0 = accC[mt][ct][0] * s4[ct][0], c1 = accC[mt][ct][1] * s4[ct][1];
                        float c2 = accC[mt][ct][2] * s4[ct][2], c3 = accC[mt][ct][3] * s4[ct][3];
                        w0 = (unsigned int)f2bf(c0) | ((unsigned int)f2bf(c1) << 16);
                        w1 = (unsigned int)f2bf(c2) | ((unsigned int)f2bf(c3) << 16);
                    }
                    uint2 v; v.x = w0; v.y = w1;
                    *(uint2*)(lds + pix * 32 +
                              ((ct * 2 + (q >> 1) + n + (n >> 2)) & 3) * 8 + (q & 1) * 4) = v;
                }
            }
            __syncthreads();
            // 128 px * 64B = 8 KB -> 512 uint4 -> 2 iterations of 256 thr
            const unsigned short* obase = out + (long)(b * 2 + pl) * HW * 32;
#pragma unroll
            for (int it = 0; it < 2; ++it) {
                int off = it * 256 + tid;          // 16B units
                int pix = off >> 2, sub = off & 3;
                uint4 v = *(const uint4*)(lds + pix * 32 + ((sub + pix + (pix >> 2)) & 3) * 8);
                int ry = pix >> 4, rx = pix & 15;
                *(uint4*)(obase + ((long)(oy0 + ry) * W + ox0 + rx) * 32 + sub * 8) = v;
            }
        }
    } else {
        float4f w74[2];
        w74[0] = *(const float4f*)(w7 + q * 4);
        w74[1] = *(const float4f*)(w7 + 16 + q * 4);
        const float b7v = b7[0];
#pragma unroll
        for (int mt = 0; mt < 2; ++mt) {
            float num = 0.f, den = 0.f;
#pragma unroll
            for (int ct = 0; ct < 2; ++ct)
#pragma unroll
                for (int r = 0; r < 4; ++r) {
                    float d = accC[mt][ct][r];
                    float oxv = fmaf(accP[mt][ct][r], frcp(d + EPSF), b4[ct][r]);
                    float oc = d * s4[ct][r];
                    num = fmaf(w74[ct][r], oxv * oc, num);
                    den = fmaf(w74[ct][r], oc, den);
                }
            num += __shfl_xor(num, 16); num += __shfl_xor(num, 32);
            den += __shfl_xor(den, 16); den += __shfl_xor(den, 32);
            if (q == 0) {
                const int oy = oy0 + 2 * wv + mt;
                const int ox = ox0 + n;
                xout[(long)b * HW + (long)oy * W + ox] = fmaf(num, frcp(den + EPSF), b7v);
            }
        }
    }
}

// ---------------------------------------------------------------------------
extern "C" void kernel_launch(void* const* d_in, const int* in_sizes, int n_in,
                              void* d_out, int out_size, void* d_ws, size_t ws_size,
                              hipStream_t stream) {
    const float* x  = (const float*)d_in[0];
    const float* w1 = (const float*)d_in[1];
    const float* b1 = (const float*)d_in[2];
    const float* w2 = (const float*)d_in[3];
    const float* b2 = (const float*)d_in[4];
    const float* w3 = (const float*)d_in[5];
    const float* b3 = (const float*)d_in[6];
    const float* w4 = (const float*)d_in[7];
    const float* b4 = (const float*)d_in[8];
    const float* w5 = (const float*)d_in[9];
    const float* b5 = (const float*)d_in[10];
    const float* w6 = (const float*)d_in[11];
    const float* b6 = (const float*)d_in[12];
    const float* w7 = (const float*)d_in[13];
    const float* b7 = (const float*)d_in[14];

    const size_t HW1 = 512 * 512, HW2s = 256 * 256, HW3s = 128 * 128, HW4s = 64 * 64;

    // ---- weight arena (400000 B) ----
    const size_t WARENA = 400000;
    float* fa = (float*)d_ws;
    float *s1 = fa, *s2 = s1 + 32, *s3 = s2 + 32;          // reciprocal sums
    float *s4 = s3 + 32, *s5 = s4 + 32, *s6 = s5 + 32;     // ends at 192 f
    unsigned int* zpage = (unsigned int*)(fa + 192);       // 16 B zeros (16B-aligned)
    unsigned short* ua = (unsigned short*)((char*)d_ws + 4096);
    unsigned short *wf2 = ua;              // 25600
    unsigned short *wf3 = wf2 + 25600;     // 25600
    unsigned short *wf4 = wf3 + 25600;     // 18432
    unsigned short *wf5 = wf4 + 18432;     // 18432
    unsigned short *wf6 = wf5 + 18432;     // 18432
    unsigned short *wf1 = wf6 + 18432;     // 1024 -> 215 KB < 400000-4096
    unsigned short* buf = (unsigned short*)((char*)d_ws + WARENA);

    // ---- stage buffers: channel-last bf16 [b*2+pc][HW][32] ----
    const size_t E1 = 2 * 2 * HW1 * 32;    // 33.55M ushort = 67.1 MB
    const size_t E2 = 2 * 2 * HW2s * 32, E3 = 2 * 2 * HW3s * 32, E4 = 2 * 2 * HW4s * 32;
    unsigned short* A = buf;
    unsigned short* B = A + E1;
    // lower-res alias inside B (sum = 22M ushorts <= E1)
    unsigned short* P = B;
    unsigned short* Q = P + E2;
    unsigned short* S = Q + E2;
    unsigned short* T = S + E3;
    unsigned short* U = T + E3;
    unsigned short* V = U + E4;

    if (ws_size < WARENA + 2 * E1 * sizeof(unsigned short)) return;  // 134.62 MB

    // ---- weight prep: single launch (frag blocks + 48 wave-sum blocks) ----
    wprep_k<<<472, 256, 0, stream>>>(w1, w2, w3, w4, w5, w6,
                                     s1, s2, s3, s4, s5, s6,
                                     wf2, wf3, wf4, wf5, wf6, wf1, zpage);

    dim3 blkm(256);
    dim3 g1(32, 64, 2), g2(16, 32, 2), g3(8, 16, 2), g4(4, 8, 2);  // 16x8 tiles

    // ---- encoder ----
    conv1_k<<<g1, blkm, 0, stream>>>(x, wf1, b1, s1, A, 512, 512);
    mconv_k<5, 1, false, false><<<g1, blkm, 0, stream>>>(A, nullptr, wf2, b2, s2, B, nullptr, nullptr, nullptr, nullptr, zpage, 512, 512);
    mconv_k<5, 1, false, true><<<g1, blkm, 0, stream>>>(B, nullptr, wf3, b3, s3, A, nullptr, nullptr, nullptr, P, zpage, 512, 512);   // x1 in A, pooled -> P

    mconv_k<5, 1, false, false><<<g2, blkm, 0, stream>>>(P, nullptr, wf2, b2, s2, Q, nullptr, nullptr, nullptr, nullptr, zpage, 256, 256);
    mconv_k<5, 1, false, true><<<g2, blkm, 0, stream>>>(Q, nullptr, wf3, b3, s3, P, nullptr, nullptr, nullptr, S, zpage, 256, 256);   // x2 in P, pooled -> S

    mconv_k<5, 1, false, true><<<g3, blkm, 0, stream>>>(S, nullptr, wf2, b2, s2, T, nullptr, nullptr, nullptr, U, zpage, 128, 128);   // x3 in T, pooled -> U

    mconv_k<5, 1, false, false><<<g4, blkm, 0, stream>>>(U, nullptr, wf2, b2, s2, V, nullptr, nullptr, nullptr, nullptr, zpage, 64, 64);  // x4 in V

    // ---- decoder ----
    mconv_k<3, 2, false, false><<<g3, blkm, 0, stream>>>(T, V, wf4, b4, s4, S, nullptr, nullptr, nullptr, nullptr, zpage, 128, 128);  // x34 in S
    mconv_k<3, 2, false, false><<<g2, blkm, 0, stream>>>(P, S, wf5, b5, s5, Q, nullptr, nullptr, nullptr, nullptr, zpage, 256, 256);  // x23 in Q
    mconv_k<3, 2, true, false><<<g1, blkm, 0, stream>>>(A, Q, wf6, b6, s6, nullptr, (float*)d_out, w7, b7, nullptr, zpage, 512, 512);
}